// Round 3
// baseline (148.799 us; speedup 1.0000x reference)
//
#include <hip/hip_runtime.h>

typedef __attribute__((ext_vector_type(8))) short short8_t;
typedef __attribute__((ext_vector_type(4))) float f32x4;

#define AS1 __attribute__((address_space(1)))
#define AS3 __attribute__((address_space(3)))

static_assert(sizeof(short8_t) == 16, "short8_t must be 16B");

__device__ __forceinline__ short f2bf(float f) {
  union { float f; unsigned u; } v; v.f = f;
  unsigned r = (v.u + 0x7FFFu + ((v.u >> 16) & 1u)) >> 16;
  return (short)r;
}
__device__ __forceinline__ float bf2f(short s) {
  union { unsigned u; float f; } v; v.u = ((unsigned)(unsigned short)s) << 16;
  return v.f;
}

// ---------------- CSR: degree count ----------------
__global__ __launch_bounds__(256) void count_deg(const int* __restrict__ ei,
                                                 int* __restrict__ deg, int E) {
  int e = blockIdx.x * 256 + threadIdx.x;
  if (e < E) atomicAdd(&deg[ei[e]], 1);
}

// N=4096 fixed: 1024 threads, 4 elems each; Hillis-Steele on partials.
__global__ __launch_bounds__(1024) void scan_deg(const int* __restrict__ deg,
                                                 int* __restrict__ rp,
                                                 float* __restrict__ dis) {
  __shared__ int part[1024];
  const int t = threadIdx.x;
  int4 v = ((const int4*)deg)[t];
  const int s = v.x + v.y + v.z + v.w;
  part[t] = s;
  __syncthreads();
  for (int off = 1; off < 1024; off <<= 1) {
    int mine = part[t];
    int add = (t >= off) ? part[t - off] : 0;
    __syncthreads();
    part[t] = mine + add;
    __syncthreads();
  }
  const int excl = part[t] - s;
  const int b4 = t * 4;
  rp[b4 + 0] = excl;
  rp[b4 + 1] = excl + v.x;
  rp[b4 + 2] = excl + v.x + v.y;
  rp[b4 + 3] = excl + v.x + v.y + v.z;
  if (t == 1023) rp[4096] = part[1023];
  dis[b4 + 0] = rsqrtf((float)(v.x + 1));
  dis[b4 + 1] = rsqrtf((float)(v.y + 1));
  dis[b4 + 2] = rsqrtf((float)(v.z + 1));
  dis[b4 + 3] = rsqrtf((float)(v.w + 1));
}

// ---------------- merged prep: CSR fill | x-transpose->xs bf16 | weight casts --
__global__ __launch_bounds__(256) void prep(
    const int* __restrict__ ei, const int* __restrict__ rp, int* __restrict__ fil,
    int* __restrict__ cols, int E,
    const float* __restrict__ x, const float* __restrict__ dis, short* __restrict__ xs,
    const float* __restrict__ W1, const float* __restrict__ W2, const float* __restrict__ W3,
    const float* __restrict__ g1, const float* __restrict__ be1,
    const float* __restrict__ g2, const float* __restrict__ be2,
    short* __restrict__ w1t, short* __restrict__ w2t, short* __restrict__ w3t,
    float* __restrict__ cs2, float* __restrict__ ct2,
    float* __restrict__ cs3, float* __restrict__ ct3) {
  __shared__ float tile[32][33];
  const int tx = threadIdx.x, ty = threadIdx.y;
  const int bid = blockIdx.x;
  if (bid < 256) {  // CSR fill
    const int e = bid * 256 + ty * 32 + tx;
    if (e < E) {
      const int r = ei[e], c = ei[E + e];
      const int p = atomicAdd(&fil[r], 1);
      cols[rp[r] + p] = c;
    }
    return;
  }
  if (bid < 256 + 4096) {  // x [B][C][N] -> xs [N][B*C] bf16, scaled by dis[n]
    const int id = bid - 256;
    const int b = id >> 10;
    const int n0 = ((id & 1023) >> 3) * 32;
    const int c0 = (id & 7) * 32;
    const float* xb = x + (long)b * (256 * 4096);
#pragma unroll
    for (int i = 0; i < 32; i += 8)
      tile[ty + i][tx] = xb[(long)(c0 + ty + i) * 4096 + n0 + tx];
    __syncthreads();
#pragma unroll
    for (int i = 0; i < 32; i += 8) {
      const int n = n0 + ty + i;
      xs[(long)n * 1024 + b * 256 + c0 + tx] = f2bf(tile[tx][ty + i] * dis[n]);
    }
    return;
  }
  // weight cast: Wt[n][k] = bf16(g_prev[k]*W[k][n]); cs[n]=sum_k g*W; ct[n]=sum_k be*W
  int id = bid - 4352;
  const float *Wf, *g = nullptr, *be = nullptr;
  float *cs = nullptr, *ctp = nullptr;
  short* Wt;
  int K, N, k0, n0;
  if (id < 256)      { Wf = W1; Wt = w1t; K = 256;  N = 1024; k0 = (id & 7) * 32;  n0 = (id >> 3) * 32; }
  else if (id < 768) { id -= 256; Wf = W2; Wt = w2t; K = 1024; N = 512; k0 = (id & 31) * 32; n0 = (id >> 5) * 32;
                       g = g1; be = be1; cs = cs2; ctp = ct2; }
  else               { id -= 768; Wf = W3; Wt = w3t; K = 512;  N = 256; k0 = (id & 15) * 32; n0 = (id >> 4) * 32;
                       g = g2; be = be2; cs = cs3; ctp = ct3; }
  float csp = 0.f, ctv = 0.f;
#pragma unroll
  for (int i = 0; i < 32; i += 8) {
    const int k = k0 + ty + i;
    const float wv = Wf[(long)k * N + n0 + tx];
    const float gk = g ? g[k] : 1.0f;
    tile[ty + i][tx] = gk * wv;
    csp += gk * wv;
    if (be) ctv += be[k] * wv;
  }
  __syncthreads();
#pragma unroll
  for (int i = 0; i < 32; i += 8)
    Wt[(long)(n0 + ty + i) * K + k0 + tx] = f2bf(tile[tx][ty + i]);
  if (cs) {
    atomicAdd(&cs[n0 + tx], csp);
    atomicAdd(&ctp[n0 + tx], ctv);
  }
}

// -------- gather: one block per node, all 4 batches; xs[n][1024] bf16 --------
// Neighbor loop unrolled x4 so 4 independent row-loads are in flight (the
// serial dependent-load chain was ~600cy/iter latency-bound).
__global__ __launch_bounds__(256) void gather_mp(const short* __restrict__ xs,
                                                 const float* __restrict__ dis,
                                                 const int* __restrict__ rp,
                                                 const int* __restrict__ cols,
                                                 short* __restrict__ h0) {
  __shared__ int sc[256];
  const int m = blockIdx.x;
  const int t = threadIdx.x;
  short4 v0 = ((const short4*)(xs + (long)m * 1024))[t];
  float a0 = bf2f(v0.x), a1 = bf2f(v0.y), a2 = bf2f(v0.z), a3 = bf2f(v0.w);
  const int s = rp[m], e = rp[m + 1];
  for (int base = s; base < e; base += 256) {
    const int cnt = min(256, e - base);
    __syncthreads();
    if (t < cnt) sc[t] = cols[base + t];
    __syncthreads();
    int j = 0;
    for (; j + 4 <= cnt; j += 4) {
      const int n0 = sc[j], n1 = sc[j + 1], n2 = sc[j + 2], n3 = sc[j + 3];
      short4 w0 = ((const short4*)(xs + (long)n0 * 1024))[t];
      short4 w1 = ((const short4*)(xs + (long)n1 * 1024))[t];
      short4 w2 = ((const short4*)(xs + (long)n2 * 1024))[t];
      short4 w3 = ((const short4*)(xs + (long)n3 * 1024))[t];
      a0 += bf2f(w0.x) + bf2f(w1.x) + bf2f(w2.x) + bf2f(w3.x);
      a1 += bf2f(w0.y) + bf2f(w1.y) + bf2f(w2.y) + bf2f(w3.y);
      a2 += bf2f(w0.z) + bf2f(w1.z) + bf2f(w2.z) + bf2f(w3.z);
      a3 += bf2f(w0.w) + bf2f(w1.w) + bf2f(w2.w) + bf2f(w3.w);
    }
    for (; j < cnt; ++j) {
      const int n = sc[j];
      short4 v = ((const short4*)(xs + (long)n * 1024))[t];
      a0 += bf2f(v.x); a1 += bf2f(v.y); a2 += bf2f(v.z); a3 += bf2f(v.w);
    }
  }
  const float d = dis[m];
  short4 o;
  o.x = f2bf(a0 * d); o.y = f2bf(a1 * d); o.z = f2bf(a2 * d); o.w = f2bf(a3 * d);
  const int b = t >> 6, c4 = t & 63;
  ((short4*)(h0 + (((long)b << 12) + m) * 256))[c4] = o;
}

// ---------------- GEMM with LN-in correction + stats-out epilogue ------------
// A[M][K] bf16, Bt[N][K] bf16 (g-prescaled). 128x128 tile, BK=32, 2x2 waves.
// T3/T4: 3-buffer ring, stage issued 2 iters ahead, raw s_barrier with
// counted vmcnt(4) (4 global_load_lds per wave per stage) — never drain to 0
// in the main loop. Final iteration peeled with vmcnt(0).
template <bool LNIN, bool RELU>
__global__ __launch_bounds__(256, 2) void gemm_ln(
    const short* __restrict__ A, const short* __restrict__ Bt,
    const float* __restrict__ bias, const float* __restrict__ cs,
    const float* __restrict__ ct, const float* __restrict__ statsIn,
    float* __restrict__ statsOut, short* __restrict__ out,
    int M, int N, int K) {
  __shared__ __align__(16) short As[3][128 * 32];
  __shared__ __align__(16) short Bs[3][128 * 32];
  const int tid = threadIdx.x;
  const int lane = tid & 63;
  const int wave = tid >> 6;
  const int wm = wave >> 1, wn = wave & 1;
  const int m0 = blockIdx.x * 128, n0 = blockIdx.y * 128;

  f32x4 acc[4][4] = {};

  const int srow = wave * 32 + (lane >> 2);
  const int scol = (lane & 3) * 8;
  const short* ag = A + (long)(m0 + srow) * K + scol;
  const short* bg = Bt + (long)(n0 + srow) * K + scol;
  const int ldst = (wave * 32) * 32;
  const int fr = lane & 15;
  const int kc = (lane >> 4) * 8;
  const int NT = K >> 5;

#define STAGE(T, BUF)                                                                        \
  do {                                                                                       \
    const short* a_ = ag + (T) * 32;                                                         \
    const short* b_ = bg + (T) * 32;                                                         \
    __builtin_amdgcn_global_load_lds((const AS1 void*)a_, (AS3 void*)(&As[BUF][ldst]), 16, 0, 0); \
    __builtin_amdgcn_global_load_lds((const AS1 void*)(a_ + 16 * K), (AS3 void*)(&As[BUF][ldst + 512]), 16, 0, 0); \
    __builtin_amdgcn_global_load_lds((const AS1 void*)b_, (AS3 void*)(&Bs[BUF][ldst]), 16, 0, 0); \
    __builtin_amdgcn_global_load_lds((const AS1 void*)(b_ + 16 * K), (AS3 void*)(&Bs[BUF][ldst + 512]), 16, 0, 0); \
  } while (0)

#define COMPUTE(RB)                                                                          \
  do {                                                                                       \
    short8_t af[4], bf[4];                                                                   \
    _Pragma("unroll")                                                                        \
    for (int i = 0; i < 4; ++i)                                                              \
      af[i] = *(const short8_t*)&As[RB][(wm * 64 + i * 16 + fr) * 32 + kc];                  \
    _Pragma("unroll")                                                                        \
    for (int i = 0; i < 4; ++i)                                                              \
      bf[i] = *(const short8_t*)&Bs[RB][(wn * 64 + i * 16 + fr) * 32 + kc];                  \
    _Pragma("unroll")                                                                        \
    for (int mi = 0; mi < 4; ++mi)                                                           \
      _Pragma("unroll")                                                                      \
      for (int ni = 0; ni < 4; ++ni)                                                         \
        acc[mi][ni] = __builtin_amdgcn_mfma_f32_16x16x32_bf16(af[mi], bf[ni],                \
                                                              acc[mi][ni], 0, 0, 0);         \
  } while (0)

  STAGE(0, 0);
  STAGE(1, 1);
  int rb = 0;  // buffer holding tile t
  for (int t = 0; t < NT - 1; ++t) {
    // stage t landed (<=4 outstanding = stage t+1); every wave waits before
    // the barrier, so after it ALL waves' stage-t data is in LDS.
    asm volatile("s_waitcnt vmcnt(4)" ::: "memory");
    __builtin_amdgcn_s_barrier();          // also fences iter t-1 reads vs ring reuse
    __builtin_amdgcn_sched_barrier(0);
    int wb = rb + 2; if (wb >= 3) wb -= 3;
    if (t + 2 < NT) STAGE(t + 2, wb);
    COMPUTE(rb);
    rb = (rb == 2) ? 0 : rb + 1;
  }
  asm volatile("s_waitcnt vmcnt(0)" ::: "memory");  // last stage landed
  __builtin_amdgcn_s_barrier();
  __builtin_amdgcn_sched_barrier(0);
  COMPUTE(rb);
#undef STAGE
#undef COMPUTE

  // epilogue: C/D layout col=lane&15, row=(lane>>4)*4+reg (m91-verified)
  const int rq = (lane >> 4) * 4;
  const float invK = 1.0f / (float)K;
  float bv[4], csv[4], ctv[4];
#pragma unroll
  for (int ni = 0; ni < 4; ++ni) {
    const int col = n0 + wn * 64 + ni * 16 + fr;
    bv[ni] = bias[col];
    if (LNIN) { csv[ni] = cs[col]; ctv[ni] = ct[col]; }
  }
#pragma unroll
  for (int mi = 0; mi < 4; ++mi) {
    float r1[4], rmu[4];
    if (LNIN) {
#pragma unroll
      for (int r = 0; r < 4; ++r) {
        const int row = m0 + wm * 64 + mi * 16 + rq + r;
        const float s = statsIn[row * 2];
        const float q = statsIn[row * 2 + 1];
        const float mu = s * invK;
        const float var = fmaxf(q * invK - mu * mu, 0.0f);
        const float rr = rsqrtf(var + 1e-5f);
        r1[r] = rr; rmu[r] = rr * mu;
      }
    }
    float sv[4] = {0, 0, 0, 0}, qv[4] = {0, 0, 0, 0};
#pragma unroll
    for (int ni = 0; ni < 4; ++ni) {
      const int col = n0 + wn * 64 + ni * 16 + fr;
#pragma unroll
      for (int r = 0; r < 4; ++r) {
        const int row = m0 + wm * 64 + mi * 16 + rq + r;
        float v = acc[mi][ni][r];
        if (LNIN) v = r1[r] * v - rmu[r] * csv[ni] + ctv[ni] + bv[ni];
        else      v = v + bv[ni];
        if (RELU) v = fmaxf(v, 0.0f);
        out[(long)row * N + col] = f2bf(v);
        sv[r] += v; qv[r] += v * v;
      }
    }
#pragma unroll
    for (int r = 0; r < 4; ++r) {
      float s = sv[r], q = qv[r];
#pragma unroll
      for (int off = 1; off < 16; off <<= 1) {
        s += __shfl_xor(s, off);
        q += __shfl_xor(q, off);
      }
      if (fr == 0) {
        const int row = m0 + wm * 64 + mi * 16 + rq + r;
        atomicAdd(&statsOut[row * 2], s);
        atomicAdd(&statsOut[row * 2 + 1], q);
      }
    }
  }
}

// ------- final LN (stats precomputed by gemm3) + transpose to [B][C][N] ------
__global__ __launch_bounds__(256) void ln_tr_out(const short* __restrict__ t3,
                                                 const float* __restrict__ stats,
                                                 const float* __restrict__ g,
                                                 const float* __restrict__ be,
                                                 float* __restrict__ out) {
  __shared__ short tile[64][66];
  const int tx = threadIdx.x;  // 64
  const int ty = threadIdx.y;  // 4
  const int n0 = blockIdx.x * 64;
  const int c0 = blockIdx.y * 64;
  const int b = blockIdx.z;
  const long rbase = ((long)b << 12) + n0;
#pragma unroll
  for (int i = ty; i < 64; i += 4)
    tile[i][tx] = t3[(rbase + i) * 256 + c0 + tx];
  const float s = stats[(rbase + tx) * 2];
  const float q = stats[(rbase + tx) * 2 + 1];
  const float mu = s * (1.0f / 256.0f);
  const float var = fmaxf(q * (1.0f / 256.0f) - mu * mu, 0.0f);
  const float inv = rsqrtf(var + 1e-5f);
  __syncthreads();
  float* ob = out + ((long)b << 20) + n0 + tx;
#pragma unroll
  for (int i = ty; i < 64; i += 4) {
    const int c = c0 + i;
    ob[(long)c * 4096] = (bf2f(tile[tx][i]) - mu) * inv * g[c] + be[c];
  }
}

extern "C" void kernel_launch(void* const* d_in, const int* in_sizes, int n_in,
                              void* d_out, int out_size, void* d_ws, size_t ws_size,
                              hipStream_t stream) {
  (void)n_in; (void)out_size; (void)ws_size;
  const float* x   = (const float*)d_in[0];
  const int*   ei  = (const int*)d_in[1];
  const float* W1  = (const float*)d_in[2];
  const float* b1  = (const float*)d_in[3];
  const float* g1  = (const float*)d_in[4];
  const float* be1 = (const float*)d_in[5];
  const float* W2  = (const float*)d_in[6];
  const float* b2  = (const float*)d_in[7];
  const float* g2  = (const float*)d_in[8];
  const float* be2 = (const float*)d_in[9];
  const float* W3  = (const float*)d_in[10];
  const float* b3  = (const float*)d_in[11];
  const float* go  = (const float*)d_in[12];
  const float* bo  = (const float*)d_in[13];
  float* out = (float*)d_out;
  const int E = in_sizes[1] / 2;  // 65536

  // workspace layout (~75MB)
  char* w = (char*)d_ws;
  int*   deg    = (int*)(w + 0);              // 16K  (zeroed)
  int*   fil    = (int*)(w + (16 << 10));     // 16K  (zeroed)
  float* stats1 = (float*)(w + (32 << 10));   // 128K (zeroed)
  float* stats2 = (float*)(w + (160 << 10));  // 128K (zeroed)
  float* stats3 = (float*)(w + (288 << 10));  // 128K (zeroed)
  float* cs2    = (float*)(w + (416 << 10));  // 2K   (zeroed)
  float* ct2    = (float*)(w + (418 << 10));  // 2K   (zeroed)
  float* cs3    = (float*)(w + (420 << 10));  // 1K   (zeroed)
  float* ct3    = (float*)(w + (421 << 10));  // 1K   (zeroed)
  int*   rp   = (int*)(w + (424 << 10));      // 16.4K
  float* dis  = (float*)(w + (444 << 10));    // 16K
  int*   cols = (int*)(w + (460 << 10));      // 256K
  short* w1t  = (short*)(w + (720 << 10));    // 512K
  short* w2t  = (short*)(w + (1240 << 10));   // 1M
  short* w3t  = (short*)(w + (2264 << 10));   // 256K
  short* xs   = (short*)(w + (3ull << 20));   // 8M  [4096][1024] bf16
  short* h0   = (short*)(w + (11ull << 20));  // 8M  [16384][256]
  short* t1   = (short*)(w + (19ull << 20));  // 32M [16384][1024]
  short* t2   = (short*)(w + (51ull << 20));  // 16M [16384][512]
  short* t3   = (short*)(w + (67ull << 20));  // 8M  [16384][256]

  hipMemsetAsync(d_ws, 0, 422 << 10, stream);
  count_deg<<<256, 256, 0, stream>>>(ei, deg, E);
  scan_deg<<<1, 1024, 0, stream>>>(deg, rp, dis);
  prep<<<5248, dim3(32, 8), 0, stream>>>(ei, rp, fil, cols, E, x, dis, xs,
                                         W1, W2, W3, g1, be1, g2, be2,
                                         w1t, w2t, w3t, cs2, ct2, cs3, ct3);
  gather_mp<<<4096, 256, 0, stream>>>(xs, dis, rp, cols, h0);
  gemm_ln<false, true><<<dim3(128, 8), 256, 0, stream>>>(
      h0, w1t, b1, nullptr, nullptr, nullptr, stats1, t1, 16384, 1024, 256);
  gemm_ln<true, true><<<dim3(128, 4), 256, 0, stream>>>(
      t1, w2t, b2, cs2, ct2, stats1, stats2, t2, 16384, 512, 1024);
  gemm_ln<true, false><<<dim3(128, 2), 256, 0, stream>>>(
      t2, w3t, b3, cs3, ct3, stats2, stats3, t3, 16384, 256, 512);
  ln_tr_out<<<dim3(64, 4, 4), dim3(64, 4), 0, stream>>>(t3, stats3, go, bo, out);
}

// Round 7
// 147.357 us; speedup vs baseline: 1.0098x; 1.0098x over previous
//
#include <hip/hip_runtime.h>

typedef __attribute__((ext_vector_type(8))) short short8_t;
typedef __attribute__((ext_vector_type(4))) float f32x4;

#define AS1 __attribute__((address_space(1)))
#define AS3 __attribute__((address_space(3)))

static_assert(sizeof(short8_t) == 16, "short8_t must be 16B");

__device__ __forceinline__ short f2bf(float f) {
  union { float f; unsigned u; } v; v.f = f;
  unsigned r = (v.u + 0x7FFFu + ((v.u >> 16) & 1u)) >> 16;
  return (short)r;
}
__device__ __forceinline__ float bf2f(short s) {
  union { unsigned u; float f; } v; v.u = ((unsigned)(unsigned short)s) << 16;
  return v.f;
}

// ---------------- CSR: degree count ----------------
__global__ __launch_bounds__(256) void count_deg(const int* __restrict__ ei,
                                                 int* __restrict__ deg, int E) {
  int e = blockIdx.x * 256 + threadIdx.x;
  if (e < E) atomicAdd(&deg[ei[e]], 1);
}

// N=4096 fixed: 1024 threads, 4 elems each; Hillis-Steele on partials.
__global__ __launch_bounds__(1024) void scan_deg(const int* __restrict__ deg,
                                                 int* __restrict__ rp,
                                                 float* __restrict__ dis) {
  __shared__ int part[1024];
  const int t = threadIdx.x;
  int4 v = ((const int4*)deg)[t];
  const int s = v.x + v.y + v.z + v.w;
  part[t] = s;
  __syncthreads();
  for (int off = 1; off < 1024; off <<= 1) {
    int mine = part[t];
    int add = (t >= off) ? part[t - off] : 0;
    __syncthreads();
    part[t] = mine + add;
    __syncthreads();
  }
  const int excl = part[t] - s;
  const int b4 = t * 4;
  rp[b4 + 0] = excl;
  rp[b4 + 1] = excl + v.x;
  rp[b4 + 2] = excl + v.x + v.y;
  rp[b4 + 3] = excl + v.x + v.y + v.z;
  if (t == 1023) rp[4096] = part[1023];
  dis[b4 + 0] = rsqrtf((float)(v.x + 1));
  dis[b4 + 1] = rsqrtf((float)(v.y + 1));
  dis[b4 + 2] = rsqrtf((float)(v.z + 1));
  dis[b4 + 3] = rsqrtf((float)(v.w + 1));
}

// ---------------- merged prep: CSR fill | x-transpose->xs bf16 | weight casts --
__global__ __launch_bounds__(256) void prep(
    const int* __restrict__ ei, const int* __restrict__ rp, int* __restrict__ fil,
    int* __restrict__ cols, int E,
    const float* __restrict__ x, const float* __restrict__ dis, short* __restrict__ xs,
    const float* __restrict__ W1, const float* __restrict__ W2, const float* __restrict__ W3,
    const float* __restrict__ g1, const float* __restrict__ be1,
    const float* __restrict__ g2, const float* __restrict__ be2,
    short* __restrict__ w1t, short* __restrict__ w2t, short* __restrict__ w3t,
    float* __restrict__ cs2, float* __restrict__ ct2,
    float* __restrict__ cs3, float* __restrict__ ct3) {
  __shared__ float tile[32][33];
  const int tx = threadIdx.x, ty = threadIdx.y;
  const int bid = blockIdx.x;
  if (bid < 256) {  // CSR fill
    const int e = bid * 256 + ty * 32 + tx;
    if (e < E) {
      const int r = ei[e], c = ei[E + e];
      const int p = atomicAdd(&fil[r], 1);
      cols[rp[r] + p] = c;
    }
    return;
  }
  if (bid < 256 + 4096) {  // x [B][C][N] -> xs [N][B*C] bf16, scaled by dis[n]
    const int id = bid - 256;
    const int b = id >> 10;
    const int n0 = ((id & 1023) >> 3) * 32;
    const int c0 = (id & 7) * 32;
    const float* xb = x + (long)b * (256 * 4096);
#pragma unroll
    for (int i = 0; i < 32; i += 8)
      tile[ty + i][tx] = xb[(long)(c0 + ty + i) * 4096 + n0 + tx];
    __syncthreads();
#pragma unroll
    for (int i = 0; i < 32; i += 8) {
      const int n = n0 + ty + i;
      xs[(long)n * 1024 + b * 256 + c0 + tx] = f2bf(tile[tx][ty + i] * dis[n]);
    }
    return;
  }
  // weight cast: Wt[n][k] = bf16(g_prev[k]*W[k][n]); cs[n]=sum_k g*W; ct[n]=sum_k be*W
  int id = bid - 4352;
  const float *Wf, *g = nullptr, *be = nullptr;
  float *cs = nullptr, *ctp = nullptr;
  short* Wt;
  int K, N, k0, n0;
  if (id < 256)      { Wf = W1; Wt = w1t; K = 256;  N = 1024; k0 = (id & 7) * 32;  n0 = (id >> 3) * 32; }
  else if (id < 768) { id -= 256; Wf = W2; Wt = w2t; K = 1024; N = 512; k0 = (id & 31) * 32; n0 = (id >> 5) * 32;
                       g = g1; be = be1; cs = cs2; ctp = ct2; }
  else               { id -= 768; Wf = W3; Wt = w3t; K = 512;  N = 256; k0 = (id & 15) * 32; n0 = (id >> 4) * 32;
                       g = g2; be = be2; cs = cs3; ctp = ct3; }
  float csp = 0.f, ctv = 0.f;
#pragma unroll
  for (int i = 0; i < 32; i += 8) {
    const int k = k0 + ty + i;
    const float wv = Wf[(long)k * N + n0 + tx];
    const float gk = g ? g[k] : 1.0f;
    tile[ty + i][tx] = gk * wv;
    csp += gk * wv;
    if (be) ctv += be[k] * wv;
  }
  __syncthreads();
#pragma unroll
  for (int i = 0; i < 32; i += 8)
    Wt[(long)(n0 + ty + i) * K + k0 + tx] = f2bf(tile[tx][ty + i]);
  if (cs) {
    atomicAdd(&cs[n0 + tx], csp);
    atomicAdd(&ctp[n0 + tx], ctv);
  }
}

// -------- gather: one block per node, all 4 batches; xs[n][1024] bf16 --------
__global__ __launch_bounds__(256) void gather_mp(const short* __restrict__ xs,
                                                 const float* __restrict__ dis,
                                                 const int* __restrict__ rp,
                                                 const int* __restrict__ cols,
                                                 short* __restrict__ h0) {
  __shared__ int sc[256];
  const int m = blockIdx.x;
  const int t = threadIdx.x;
  short4 v0 = ((const short4*)(xs + (long)m * 1024))[t];
  float a0 = bf2f(v0.x), a1 = bf2f(v0.y), a2 = bf2f(v0.z), a3 = bf2f(v0.w);
  const int s = rp[m], e = rp[m + 1];
  for (int base = s; base < e; base += 256) {
    const int cnt = min(256, e - base);
    __syncthreads();
    if (t < cnt) sc[t] = cols[base + t];
    __syncthreads();
    int j = 0;
    for (; j + 4 <= cnt; j += 4) {
      const int n0 = sc[j], n1 = sc[j + 1], n2 = sc[j + 2], n3 = sc[j + 3];
      short4 w0 = ((const short4*)(xs + (long)n0 * 1024))[t];
      short4 w1 = ((const short4*)(xs + (long)n1 * 1024))[t];
      short4 w2 = ((const short4*)(xs + (long)n2 * 1024))[t];
      short4 w3 = ((const short4*)(xs + (long)n3 * 1024))[t];
      a0 += bf2f(w0.x) + bf2f(w1.x) + bf2f(w2.x) + bf2f(w3.x);
      a1 += bf2f(w0.y) + bf2f(w1.y) + bf2f(w2.y) + bf2f(w3.y);
      a2 += bf2f(w0.z) + bf2f(w1.z) + bf2f(w2.z) + bf2f(w3.z);
      a3 += bf2f(w0.w) + bf2f(w1.w) + bf2f(w2.w) + bf2f(w3.w);
    }
    for (; j < cnt; ++j) {
      const int n = sc[j];
      short4 v = ((const short4*)(xs + (long)n * 1024))[t];
      a0 += bf2f(v.x); a1 += bf2f(v.y); a2 += bf2f(v.z); a3 += bf2f(v.w);
    }
  }
  const float d = dis[m];
  short4 o;
  o.x = f2bf(a0 * d); o.y = f2bf(a1 * d); o.z = f2bf(a2 * d); o.w = f2bf(a3 * d);
  const int b = t >> 6, c4 = t & 63;
  ((short4*)(h0 + (((long)b << 12) + m) * 256))[c4] = o;
}

// ---------------- GEMM with LN-in correction + stats-out epilogue ------------
// A[M][K] bf16, Bt[N][K] bf16 (g-prescaled). 128x128 tile, BK=32, 2x2 waves.
// Spill-safe 2-buffer syncthreads pipeline (r2-verified). launch_bounds(256,3):
// 3 blocks/CU (96KB LDS, VGPR cap ~170) so a third block's waves cover the
// per-barrier vmcnt(0) drains (m114 wave-level overlap).
template <bool LNIN, bool RELU>
__global__ __launch_bounds__(256, 3) void gemm_ln(
    const short* __restrict__ A, const short* __restrict__ Bt,
    const float* __restrict__ bias, const float* __restrict__ cs,
    const float* __restrict__ ct, const float* __restrict__ statsIn,
    float* __restrict__ statsOut, short* __restrict__ out,
    int M, int N, int K) {
  __shared__ __align__(16) short As[2][128 * 32];
  __shared__ __align__(16) short Bs[2][128 * 32];
  const int tid = threadIdx.x;
  const int lane = tid & 63;
  const int wave = tid >> 6;
  const int wm = wave >> 1, wn = wave & 1;
  const int m0 = blockIdx.x * 128, n0 = blockIdx.y * 128;

  f32x4 acc[4][4] = {};

  const int srow = wave * 32 + (lane >> 2);
  const int scol = (lane & 3) * 8;
  const short* ag = A + (long)(m0 + srow) * K + scol;
  const short* bg = Bt + (long)(n0 + srow) * K + scol;
  const int ldst = (wave * 32) * 32;
  const int fr = lane & 15;
  const int kc = (lane >> 4) * 8;
  const int NT = K >> 5;

#define STAGE(T, BUF)                                                                        \
  do {                                                                                       \
    const short* a_ = ag + (T) * 32;                                                         \
    const short* b_ = bg + (T) * 32;                                                         \
    __builtin_amdgcn_global_load_lds((const AS1 void*)a_, (AS3 void*)(&As[BUF][ldst]), 16, 0, 0); \
    __builtin_amdgcn_global_load_lds((const AS1 void*)(a_ + 16 * K), (AS3 void*)(&As[BUF][ldst + 512]), 16, 0, 0); \
    __builtin_amdgcn_global_load_lds((const AS1 void*)b_, (AS3 void*)(&Bs[BUF][ldst]), 16, 0, 0); \
    __builtin_amdgcn_global_load_lds((const AS1 void*)(b_ + 16 * K), (AS3 void*)(&Bs[BUF][ldst + 512]), 16, 0, 0); \
  } while (0)

  STAGE(0, 0);
  __syncthreads();
  int cur = 0;
  for (int t = 0; t < NT; ++t) {
    if (t + 1 < NT) STAGE(t + 1, cur ^ 1);  // prefetch overlaps this tile's MFMA
    short8_t af[4], bf[4];
#pragma unroll
    for (int i = 0; i < 4; ++i)
      af[i] = *(const short8_t*)&As[cur][(wm * 64 + i * 16 + fr) * 32 + kc];
#pragma unroll
    for (int i = 0; i < 4; ++i)
      bf[i] = *(const short8_t*)&Bs[cur][(wn * 64 + i * 16 + fr) * 32 + kc];
#pragma unroll
    for (int mi = 0; mi < 4; ++mi)
#pragma unroll
      for (int ni = 0; ni < 4; ++ni)
        acc[mi][ni] = __builtin_amdgcn_mfma_f32_16x16x32_bf16(af[mi], bf[ni],
                                                              acc[mi][ni], 0, 0, 0);
    __syncthreads();  // implicit vmcnt(0): prefetch landed; buffer swap safe
    cur ^= 1;
  }
#undef STAGE

  // epilogue: C/D layout col=lane&15, row=(lane>>4)*4+reg (m91-verified)
  const int rq = (lane >> 4) * 4;
  const float invK = 1.0f / (float)K;
  float bv[4], csv[4], ctv[4];
#pragma unroll
  for (int ni = 0; ni < 4; ++ni) {
    const int col = n0 + wn * 64 + ni * 16 + fr;
    bv[ni] = bias[col];
    if (LNIN) { csv[ni] = cs[col]; ctv[ni] = ct[col]; }
  }
#pragma unroll
  for (int mi = 0; mi < 4; ++mi) {
    float r1[4], rmu[4];
    if (LNIN) {
#pragma unroll
      for (int r = 0; r < 4; ++r) {
        const int row = m0 + wm * 64 + mi * 16 + rq + r;
        const float s = statsIn[row * 2];
        const float q = statsIn[row * 2 + 1];
        const float mu = s * invK;
        const float var = fmaxf(q * invK - mu * mu, 0.0f);
        const float rr = rsqrtf(var + 1e-5f);
        r1[r] = rr; rmu[r] = rr * mu;
      }
    }
    float sv[4] = {0, 0, 0, 0}, qv[4] = {0, 0, 0, 0};
#pragma unroll
    for (int ni = 0; ni < 4; ++ni) {
      const int col = n0 + wn * 64 + ni * 16 + fr;
#pragma unroll
      for (int r = 0; r < 4; ++r) {
        const int row = m0 + wm * 64 + mi * 16 + rq + r;
        float v = acc[mi][ni][r];
        if (LNIN) v = r1[r] * v - rmu[r] * csv[ni] + ctv[ni] + bv[ni];
        else      v = v + bv[ni];
        if (RELU) v = fmaxf(v, 0.0f);
        out[(long)row * N + col] = f2bf(v);
        sv[r] += v; qv[r] += v * v;
      }
    }
#pragma unroll
    for (int r = 0; r < 4; ++r) {
      float s = sv[r], q = qv[r];
#pragma unroll
      for (int off = 1; off < 16; off <<= 1) {
        s += __shfl_xor(s, off);
        q += __shfl_xor(q, off);
      }
      if (fr == 0) {
        const int row = m0 + wm * 64 + mi * 16 + rq + r;
        atomicAdd(&statsOut[row * 2], s);
        atomicAdd(&statsOut[row * 2 + 1], q);
      }
    }
  }
}

// ------- final LN (stats precomputed by gemm3) + transpose to [B][C][N] ------
__global__ __launch_bounds__(256) void ln_tr_out(const short* __restrict__ t3,
                                                 const float* __restrict__ stats,
                                                 const float* __restrict__ g,
                                                 const float* __restrict__ be,
                                                 float* __restrict__ out) {
  __shared__ short tile[64][66];
  const int tx = threadIdx.x;  // 64
  const int ty = threadIdx.y;  // 4
  const int n0 = blockIdx.x * 64;
  const int c0 = blockIdx.y * 64;
  const int b = blockIdx.z;
  const long rbase = ((long)b << 12) + n0;
#pragma unroll
  for (int i = ty; i < 64; i += 4)
    tile[i][tx] = t3[(rbase + i) * 256 + c0 + tx];
  const float s = stats[(rbase + tx) * 2];
  const float q = stats[(rbase + tx) * 2 + 1];
  const float mu = s * (1.0f / 256.0f);
  const float var = fmaxf(q * (1.0f / 256.0f) - mu * mu, 0.0f);
  const float inv = rsqrtf(var + 1e-5f);
  __syncthreads();
  float* ob = out + ((long)b << 20) + n0 + tx;
#pragma unroll
  for (int i = ty; i < 64; i += 4) {
    const int c = c0 + i;
    ob[(long)c * 4096] = (bf2f(tile[tx][i]) - mu) * inv * g[c] + be[c];
  }
}

extern "C" void kernel_launch(void* const* d_in, const int* in_sizes, int n_in,
                              void* d_out, int out_size, void* d_ws, size_t ws_size,
                              hipStream_t stream) {
  (void)n_in; (void)out_size; (void)ws_size;
  const float* x   = (const float*)d_in[0];
  const int*   ei  = (const int*)d_in[1];
  const float* W1  = (const float*)d_in[2];
  const float* b1  = (const float*)d_in[3];
  const float* g1  = (const float*)d_in[4];
  const float* be1 = (const float*)d_in[5];
  const float* W2  = (const float*)d_in[6];
  const float* b2  = (const float*)d_in[7];
  const float* g2  = (const float*)d_in[8];
  const float* be2 = (const float*)d_in[9];
  const float* W3  = (const float*)d_in[10];
  const float* b3  = (const float*)d_in[11];
  const float* go  = (const float*)d_in[12];
  const float* bo  = (const float*)d_in[13];
  float* out = (float*)d_out;
  const int E = in_sizes[1] / 2;  // 65536

  // workspace layout (~75MB)
  char* w = (char*)d_ws;
  int*   deg    = (int*)(w + 0);              // 16K  (zeroed)
  int*   fil    = (int*)(w + (16 << 10));     // 16K  (zeroed)
  float* stats1 = (float*)(w + (32 << 10));   // 128K (zeroed)
  float* stats2 = (float*)(w + (160 << 10));  // 128K (zeroed)
  float* stats3 = (float*)(w + (288 << 10));  // 128K (zeroed)
  float* cs2    = (float*)(w + (416 << 10));  // 2K   (zeroed)
  float* ct2    = (float*)(w + (418 << 10));  // 2K   (zeroed)
  float* cs3    = (float*)(w + (420 << 10));  // 1K   (zeroed)
  float* ct3    = (float*)(w + (421 << 10));  // 1K   (zeroed)
  int*   rp   = (int*)(w + (424 << 10));      // 16.4K
  float* dis  = (float*)(w + (444 << 10));    // 16K
  int*   cols = (int*)(w + (460 << 10));      // 256K
  short* w1t  = (short*)(w + (720 << 10));    // 512K
  short* w2t  = (short*)(w + (1240 << 10));   // 1M
  short* w3t  = (short*)(w + (2264 << 10));   // 256K
  short* xs   = (short*)(w + (3ull << 20));   // 8M  [4096][1024] bf16
  short* h0   = (short*)(w + (11ull << 20));  // 8M  [16384][256]
  short* t1   = (short*)(w + (19ull << 20));  // 32M [16384][1024]
  short* t2   = (short*)(w + (51ull << 20));  // 16M [16384][512]
  short* t3   = (short*)(w + (67ull << 20));  // 8M  [16384][256]

  hipMemsetAsync(d_ws, 0, 422 << 10, stream);
  count_deg<<<256, 256, 0, stream>>>(ei, deg, E);
  scan_deg<<<1, 1024, 0, stream>>>(deg, rp, dis);
  prep<<<5248, dim3(32, 8), 0, stream>>>(ei, rp, fil, cols, E, x, dis, xs,
                                         W1, W2, W3, g1, be1, g2, be2,
                                         w1t, w2t, w3t, cs2, ct2, cs3, ct3);
  gather_mp<<<4096, 256, 0, stream>>>(xs, dis, rp, cols, h0);
  gemm_ln<false, true><<<dim3(128, 8), 256, 0, stream>>>(
      h0, w1t, b1, nullptr, nullptr, nullptr, stats1, t1, 16384, 1024, 256);
  gemm_ln<true, true><<<dim3(128, 4), 256, 0, stream>>>(
      t1, w2t, b2, cs2, ct2, stats1, stats2, t2, 16384, 512, 1024);
  gemm_ln<true, false><<<dim3(128, 2), 256, 0, stream>>>(
      t2, w3t, b3, cs3, ct3, stats2, stats3, t3, 16384, 256, 512);
  ln_tr_out<<<dim3(64, 4, 4), dim3(64, 4), 0, stream>>>(t3, stats3, go, bo, out);
}